// Round 11
// baseline (186.072 us; speedup 1.0000x reference)
//
#include <hip/hip_runtime.h>
#include <hip/hip_bf16.h>
#include <math.h>

// R11: stage2 v3 — 32-px blocks (grid 512, 2 blocks/CU), reg-double-buffered
// x staging, direct-global B-fragments (no B staging barriers). 3 dispatches.

using bf16x8 = __attribute__((ext_vector_type(8))) short;
using f32x4  = __attribute__((ext_vector_type(4))) float;

#define GLOBAL_AS __attribute__((address_space(1)))
#define LDS_AS    __attribute__((address_space(3)))

static __device__ inline void g2lds16(const void* g, void* l) {
  __builtin_amdgcn_global_load_lds((const GLOBAL_AS int*)g, (LDS_AS int*)l, 16, 0, 0);
}
static __device__ inline unsigned short f2bf(float v) {
  __hip_bfloat16 b = __float2bfloat16(v);
  return *reinterpret_cast<unsigned short*>(&b);
}
static __device__ inline float us2f(unsigned short u) {
  union { unsigned u; float f; } c; c.u = ((unsigned)u) << 16; return c.f;
}
static __device__ inline unsigned pk2(float a, float b) {
  return (unsigned)f2bf(a) | ((unsigned)f2bf(b) << 16);
}

// ---------------- weight prep: W[k][n] fp32 -> Bt[n][k] bf16 (+pad) ---------
__global__ __launch_bounds__(256) void prep_k(
    const float* __restrict__ inp_w, const float* __restrict__ off_w,
    const float* __restrict__ off_b, const float* __restrict__ mask_w,
    const float* __restrict__ mask_b, const float* __restrict__ out_w,
    __hip_bfloat16* __restrict__ BtI, __hip_bfloat16* __restrict__ BtOM,
    __hip_bfloat16* __restrict__ BtO, float* __restrict__ bOM)
{
  int b = blockIdx.x, t = threadIdx.x;   // t = k index
  if (b < 256) {
    int n = b;
    BtI[n * 256 + t] = __float2bfloat16(inp_w[t * 256 + n]);
  } else if (b < 768) {
    int n = b - 256;
    float v = 0.f;
    if (n < 288) v = off_w[t * 288 + n];
    else if (n < 432) v = mask_w[t * 144 + (n - 288)];
    BtOM[n * 256 + t] = __float2bfloat16(v);
    if (b == 256) {
      for (int idx = t; idx < 512; idx += 256) {
        float bv = (idx < 288) ? off_b[idx] : ((idx < 432) ? mask_b[idx - 288] : 0.f);
        bOM[idx] = bv;
      }
    }
  } else {
    int n = b - 768;
    BtO[n * 256 + t] = __float2bfloat16(out_w[t * 256 + n]);
  }
}

// ---------------- stage2 v3: dwconv + LN + GELU + iproj GEMM + OM GEMM ------
// block = 32 px (half image row), 512 threads (8 waves). grid 512.
// LDS 46080 B: x1t[32][264] | xs 2x[3*32][52] | wgt[9][256]; psq/murs overlay xs.
__global__ __launch_bounds__(512, 6) void stage2_k(
    const float* __restrict__ x,
    const float* __restrict__ dw_w, const float* __restrict__ dw_b,
    const float* __restrict__ ln_g, const float* __restrict__ ln_b,
    const __hip_bfloat16* __restrict__ BtI, const float* __restrict__ inp_b,
    const __hip_bfloat16* __restrict__ BtOM, const float* __restrict__ bOM,
    __hip_bfloat16* __restrict__ xpu, __hip_bfloat16* __restrict__ om)
{
  __shared__ __align__(16) char smem[46080];
  unsigned short* x1t = (unsigned short*)smem;               // [32][264] 16896 B
  unsigned short* xs  = (unsigned short*)(smem + 16896);     // 2 x 4992 shorts
  float* wgt  = (float*)(smem + 36864);                      // [9][256] 9216 B
  float* psq  = (float*)(smem + 16896);                      // overlay: 2x512 f
  float* murs = (float*)(smem + 20992);                      // overlay: 2x32 f

  const int blk = blockIdx.x;                 // n4*128 + h*2 + half
  const int n4 = blk >> 7, h = (blk >> 1) & 63;
  const int px0 = (blk & 1) * 32;
  const int t = threadIdx.x;
  const int w = t & 31, q = t >> 5;           // pixel w (0..31), ch-group q (0..15)
  const int wave = t >> 6, lane = t & 63;
  const int quad = lane >> 4, lr = lane & 15;
  const int wm = wave >> 2, wn = wave & 3;    // 2 m-tiles x 4 n-blocks

  // ---- stage full dw weights [p][c] once
  for (int i = t; i < 2304; i += 512) {
    float v = dw_w[i];                        // i = c*9 + p
    wgt[(i % 9) * 256 + (i / 9)] = v;
  }

  // ---- staging task params (tasks: 3r x 32c x 6 px-chunks = 576)
  int r0, c0, lpx0, gpx0, r1, c1, lpx1, gpx1;
  {
    int id = t;
    r0 = id / 192; int rem = id - r0 * 192; c0 = rem / 6; int cp = rem - c0 * 6;
    lpx0 = cp * 8; gpx0 = px0 - 8 + lpx0;
  }
  const bool tb2 = (t < 64);
  if (tb2) {
    int id = 512 + t;
    r1 = id / 192; int rem = id - r1 * 192; c1 = rem / 6; int cp = rem - c1 * 6;
    lpx1 = cp * 8; gpx1 = px0 - 8 + lpx1;
  }

  auto ldx = [&](int chunk, int r, int c, int gpx, float4& a, float4& b) {
    a = make_float4(0.f, 0.f, 0.f, 0.f);
    b = make_float4(0.f, 0.f, 0.f, 0.f);
    int hh = h + r - 1;
    if ((unsigned)hh < 64u && (unsigned)gpx < 57u) {
      const float* s = x + (size_t)n4 * 1048576 + (size_t)(chunk * 32 + c) * 4096 + hh * 64 + gpx;
      a = *(const float4*)s;
      b = *(const float4*)(s + 4);
    }
  };
  auto stx = [&](int buf, int r, int c, int lpx, float4 a, float4 b) {
    unsigned short* d = &xs[buf * 4992 + (r * 32 + c) * 52 + lpx];
    uint2 u0, u1;
    u0.x = pk2(a.x, a.y); u0.y = pk2(a.z, a.w);
    u1.x = pk2(b.x, b.y); u1.y = pk2(b.z, b.w);
    *(uint2*)d = u0; *(uint2*)(d + 4) = u1;
  };

  f32x4 acc_i[4];
  #pragma unroll
  for (int i = 0; i < 4; ++i) acc_i[i] = (f32x4){0.f, 0.f, 0.f, 0.f};

  float4 pa0, pb0, pa1, pb1;
  ldx(0, r0, c0, gpx0, pa0, pb0);
  if (tb2) ldx(0, r1, c1, gpx1, pa1, pb1);
  stx(0, r0, c0, lpx0, pa0, pb0);
  if (tb2) stx(0, r1, c1, lpx1, pa1, pb1);
  __syncthreads();

  float s1 = 0.f, s2 = 0.f;
  for (int chunk = 0; chunk < 8; ++chunk) {
    const int buf = chunk & 1;
    const int ch0 = chunk * 32;
    if (chunk < 7) {                         // prefetch next chunk -> regs
      ldx(chunk + 1, r0, c0, gpx0, pa0, pb0);
      if (tb2) ldx(chunk + 1, r1, c1, gpx1, pa1, pb1);
    }
    const unsigned short* xb = &xs[buf * 4992];
    {                                        // conv: 2 channels per thread
      int lc = 2 * q, c = ch0 + lc;
      float a0 = dw_b[c], a1 = dw_b[c + 1];
      #pragma unroll
      for (int p = 0; p < 9; ++p) {
        int dh = p / 3, dwd = p % 3 - 1;
        int ii = 8 + w + dwd;                // zero-padded halo: branchless
        a0 = fmaf(us2f(xb[(dh * 32 + lc) * 52 + ii]), wgt[p * 256 + c], a0);
        a1 = fmaf(us2f(xb[(dh * 32 + lc + 1) * 52 + ii]), wgt[p * 256 + c + 1], a1);
      }
      s1 += a0 + a1;
      s2 = fmaf(a0, a0, fmaf(a1, a1, s2));
      *(unsigned*)&x1t[w * 264 + c] = pk2(a0, a1);
    }
    {                                        // iproj: A from xs center row, B direct
      bf16x8 af;
      #pragma unroll
      for (int j = 0; j < 8; ++j)
        ((unsigned short*)&af)[j] = xb[(32 + quad * 8 + j) * 52 + 8 + wm * 16 + lr];
      #pragma unroll
      for (int ni = 0; ni < 4; ++ni) {
        bf16x8 bf = *(const bf16x8*)&BtI[(size_t)(wn * 64 + ni * 16 + lr) * 256 + ch0 + quad * 8];
        acc_i[ni] = __builtin_amdgcn_mfma_f32_16x16x32_bf16(af, bf, acc_i[ni], 0, 0, 0);
      }
    }
    if (chunk < 7) {                         // write prefetched into other buffer
      stx(buf ^ 1, r0, c0, lpx0, pa0, pb0);
      if (tb2) stx(buf ^ 1, r1, c1, lpx1, pa1, pb1);
    }
    __syncthreads();
  }

  // ---- xpu epilogue (regs only)
  const size_t pixb = (size_t)n4 * 4096 + (size_t)h * 64 + px0;
  #pragma unroll
  for (int ni = 0; ni < 4; ++ni) {
    int col = wn * 64 + ni * 16 + lr;
    float bv = inp_b[col];
    #pragma unroll
    for (int reg = 0; reg < 4; ++reg) {
      int m = wm * 16 + quad * 4 + reg;
      xpu[(pixb + m) * 256 + col] = __float2bfloat16(acc_i[ni][reg] + bv);
    }
  }

  // ---- LN reduce (psq overlays xs; all xs reads done)
  psq[q * 32 + w] = s1;
  psq[512 + q * 32 + w] = s2;
  __syncthreads();
  if (t < 32) {
    float a = 0.f, b = 0.f;
    #pragma unroll
    for (int j = 0; j < 16; ++j) { a += psq[j * 32 + t]; b += psq[512 + j * 32 + t]; }
    float mu = a * (1.f / 256.f);
    murs[t] = mu;
    murs[32 + t] = rsqrtf(b * (1.f / 256.f) - mu * mu + 1e-5f);
  }
  __syncthreads();
  {                                          // normalize + GELU in place
    float mu = murs[w], rs = murs[32 + w];
    #pragma unroll
    for (int chunk = 0; chunk < 8; ++chunk) {
      int c = chunk * 32 + 2 * q;
      unsigned pkv = *(const unsigned*)&x1t[w * 264 + c];
      float v0 = us2f((unsigned short)(pkv & 0xffff));
      float v1 = us2f((unsigned short)(pkv >> 16));
      float y0 = fmaf((v0 - mu) * rs, ln_g[c], ln_b[c]);
      float y1 = fmaf((v1 - mu) * rs, ln_g[c + 1], ln_b[c + 1]);
      float g0 = 0.5f * y0 * (1.f + erff(y0 * 0.70710678f));
      float g1 = 0.5f * y1 * (1.f + erff(y1 * 0.70710678f));
      *(unsigned*)&x1t[w * 264 + c] = pk2(g0, g1);
    }
  }
  __syncthreads();

  // ---- OM GEMM: M=32, N=448(432 valid), K=256; B direct global; no barriers
  f32x4 acc[7];
  #pragma unroll
  for (int i = 0; i < 7; ++i) acc[i] = (f32x4){0.f, 0.f, 0.f, 0.f};
  for (int kt = 0; kt < 256; kt += 32) {
    bf16x8 af = *(const bf16x8*)&x1t[(wm * 16 + lr) * 264 + kt + quad * 8];
    #pragma unroll
    for (int ni = 0; ni < 7; ++ni) {
      bf16x8 bf = *(const bf16x8*)&BtOM[(size_t)(wn * 112 + ni * 16 + lr) * 256 + kt + quad * 8];
      acc[ni] = __builtin_amdgcn_mfma_f32_16x16x32_bf16(af, bf, acc[ni], 0, 0, 0);
    }
  }
  #pragma unroll
  for (int ni = 0; ni < 7; ++ni) {
    int col = wn * 112 + ni * 16 + lr;
    if (col < 432) {
      float bv = bOM[col];
      #pragma unroll
      for (int reg = 0; reg < 4; ++reg) {
        int m = wm * 16 + quad * 4 + reg;
        om[(pixb + m) * 448 + col] = __float2bfloat16(acc[ni][reg] + bv);
      }
    }
  }
}

// ---------------- fused: sampling + output GEMM + NCHW store ----------------
// block = 16 px, 256 thr; LDS 39168 B -> 4 blocks/CU. XCD-swizzled.
__global__ __launch_bounds__(256) void samp_o(
    const __hip_bfloat16* __restrict__ xpu, const __hip_bfloat16* __restrict__ om,
    const __hip_bfloat16* __restrict__ BtO, const float* __restrict__ out_b,
    float* __restrict__ out)
{
  __shared__ __align__(16) char smem[39168];
  unsigned short* oms   = (unsigned short*)smem;             // 16x448 = 14336 B
  unsigned short* sampS = (unsigned short*)(smem + 14336);   // 16x264 = 8448 B
  short* Bs = (short*)(smem + 22784);                        // 256x32 = 16384 B
  float* tb = (float*)smem;                                  // epi: [256][17]

  const int bid = blockIdx.x;                // 1024
  const int region = bid & 7;                // XCD under round-robin dispatch
  const int qb = bid >> 3;
  const int pix0 = region * 2048 + qb * 16;
  const int n4 = pix0 >> 12, hw0 = pix0 & 4095;
  const int t = threadIdx.x;

  {  // stage om tile: 16 px * 448 bf16 = 896 uint4
    const uint4* gsrc = (const uint4*)(om + (size_t)pix0 * 448);
    uint4* ldst = (uint4*)oms;
    #pragma unroll
    for (int r = 0; r < 4; ++r) {
      int i = t + r * 256;
      if (i < 896) ldst[i] = gsrc[i];
    }
  }
  __syncthreads();

  {  // sampling: thread = (pixel, group)
    const int g = t & 15;
    const int pl = t >> 4;
    const int hw = hw0 + pl;
    const int h = hw >> 6, w = hw & 63;

    float mk[9];
    const unsigned short* mp = &oms[pl * 448 + 288 + g * 9];
    float mx = -1e30f;
    #pragma unroll
    for (int p = 0; p < 9; ++p) { mk[p] = us2f(mp[p]); mx = fmaxf(mx, mk[p]); }
    float se = 0.f;
    #pragma unroll
    for (int p = 0; p < 9; ++p) { mk[p] = __expf(mk[p] - mx); se += mk[p]; }
    float inv = 1.f / se;
    #pragma unroll
    for (int p = 0; p < 9; ++p) mk[p] *= inv;

    const unsigned short* op = &oms[pl * 448 + g * 18];
    const __hip_bfloat16* xpg = xpu + (g << 4);
    float ax[16];
    #pragma unroll
    for (int i = 0; i < 16; ++i) ax[i] = 0.f;

    auto corner = [&](int iy, int ix, float wt) {
      if ((unsigned)(iy - 1) >= 64u || (unsigned)(ix - 1) >= 64u) return;
      const __hip_bfloat16* src =
          xpg + ((size_t)((n4 << 12) + (iy - 1) * 64 + (ix - 1)) << 8);
      uint4 u0 = *(const uint4*)src;
      uint4 u1 = *(const uint4*)(src + 8);
      const unsigned uu[8] = {u0.x, u0.y, u0.z, u0.w, u1.x, u1.y, u1.z, u1.w};
      #pragma unroll
      for (int i = 0; i < 8; ++i) {
        float lo = us2f((unsigned short)(uu[i] & 0xffff));
        float hi = us2f((unsigned short)(uu[i] >> 16));
        ax[2 * i + 0] = fmaf(wt, lo, ax[2 * i + 0]);
        ax[2 * i + 1] = fmaf(wt, hi, ax[2 * i + 1]);
      }
    };

    #pragma unroll
    for (int p = 0; p < 9; ++p) {
      float ox = us2f(op[2 * p]), oy = us2f(op[2 * p + 1]);
      float px = (float)(w + p / 3) + ox;
      float py = (float)(h + p % 3) + oy;
      float xf = floorf(px), yf = floorf(py);
      float wx = px - xf, wy = py - yf;
      int ix = (int)xf, iy = (int)yf;
      float m = mk[p];
      corner(iy,     ix,     (1.f - wy) * (1.f - wx) * m);
      corner(iy,     ix + 1, (1.f - wy) * wx * m);
      corner(iy + 1, ix,     wy * (1.f - wx) * m);
      corner(iy + 1, ix + 1, wy * wx * m);
    }

    unsigned short ub[16];
    #pragma unroll
    for (int i = 0; i < 16; ++i) ub[i] = f2bf(ax[i]);
    uint4 u0, u1;
    u0.x = (unsigned)ub[0] | ((unsigned)ub[1] << 16);
    u0.y = (unsigned)ub[2] | ((unsigned)ub[3] << 16);
    u0.z = (unsigned)ub[4] | ((unsigned)ub[5] << 16);
    u0.w = (unsigned)ub[6] | ((unsigned)ub[7] << 16);
    u1.x = (unsigned)ub[8] | ((unsigned)ub[9] << 16);
    u1.y = (unsigned)ub[10] | ((unsigned)ub[11] << 16);
    u1.z = (unsigned)ub[12] | ((unsigned)ub[13] << 16);
    u1.w = (unsigned)ub[14] | ((unsigned)ub[15] << 16);
    *(uint4*)&sampS[pl * 264 + g * 16] = u0;
    *(uint4*)&sampS[pl * 264 + g * 16 + 8] = u1;
  }
  __syncthreads();

  // GEMM: M=16, N=256, K=256; 4 waves = 4 n-quadrants of 64 cols.
  const int wave = t >> 6, lane = t & 63;
  const int quad = lane >> 4, lr = lane & 15;
  f32x4 acc[4];
  #pragma unroll
  for (int i = 0; i < 4; ++i) acc[i] = (f32x4){0.f, 0.f, 0.f, 0.f};

  for (int kt = 0; kt < 256; kt += 32) {
    if (kt) __syncthreads();                 // prev-iter Bs reads done
    #pragma unroll
    for (int j = 0; j < 4; ++j) {            // 1024 chunks of 16 B
      int idx = j * 256 + t;
      int col = idx >> 2, kq = idx & 3;
      g2lds16(BtO + (size_t)col * 256 + kt + kq * 8, (char*)Bs + idx * 16);
    }
    __syncthreads();
    bf16x8 af = *(const bf16x8*)&sampS[lr * 264 + kt + quad * 8];
    #pragma unroll
    for (int ni = 0; ni < 4; ++ni) {
      bf16x8 bf = *(const bf16x8*)&Bs[(wave * 64 + ni * 16 + lr) * 32 + quad * 8];
      acc[ni] = __builtin_amdgcn_mfma_f32_16x16x32_bf16(af, bf, acc[ni], 0, 0, 0);
    }
  }
  __syncthreads();                           // sampS/oms dead; tb overlays

  #pragma unroll
  for (int ni = 0; ni < 4; ++ni) {
    int col = wave * 64 + ni * 16 + lr;
    float bv = out_b[col];
    #pragma unroll
    for (int reg = 0; reg < 4; ++reg)
      tb[col * 17 + quad * 4 + reg] = acc[ni][reg] + bv;
  }
  __syncthreads();

  {  // thread t = channel; 16 px contiguous -> 4 float4 stores
    int co = t;
    float* dst = out + (size_t)(n4 * 256 + co) * 4096 + hw0;
    #pragma unroll
    for (int j = 0; j < 4; ++j) {
      float4 v;
      v.x = tb[co * 17 + j * 4 + 0];
      v.y = tb[co * 17 + j * 4 + 1];
      v.z = tb[co * 17 + j * 4 + 2];
      v.w = tb[co * 17 + j * 4 + 3];
      *(float4*)(dst + j * 4) = v;
    }
  }
}

extern "C" void kernel_launch(void* const* d_in, const int* in_sizes, int n_in,
                              void* d_out, int out_size, void* d_ws, size_t ws_size,
                              hipStream_t stream) {
  const float* x      = (const float*)d_in[0];
  const float* dw_w   = (const float*)d_in[1];
  const float* dw_b   = (const float*)d_in[2];
  const float* ln_g   = (const float*)d_in[3];
  const float* ln_b   = (const float*)d_in[4];
  const float* off_w  = (const float*)d_in[5];
  const float* off_b  = (const float*)d_in[6];
  const float* mask_w = (const float*)d_in[7];
  const float* mask_b = (const float*)d_in[8];
  const float* inp_w  = (const float*)d_in[9];
  const float* inp_b  = (const float*)d_in[10];
  const float* out_w  = (const float*)d_in[11];
  const float* out_b  = (const float*)d_in[12];
  float* out = (float*)d_out;

  char* w0 = (char*)d_ws;
  __hip_bfloat16* xpu  = (__hip_bfloat16*)(w0);               //  8,388,608 B
  __hip_bfloat16* om   = (__hip_bfloat16*)(w0 + 8388608);     // 14,680,064 B
  __hip_bfloat16* BtI  = (__hip_bfloat16*)(w0 + 23068672);    //    131,072 B
  __hip_bfloat16* BtOM = (__hip_bfloat16*)(w0 + 23199744);    //    262,144 B
  __hip_bfloat16* BtO  = (__hip_bfloat16*)(w0 + 23461888);    //    131,072 B
  float*          bOM  = (float*)(w0 + 23592960);             //      2,048 B
  if (ws_size < 23595008) return;

  prep_k<<<1024, 256, 0, stream>>>(inp_w, off_w, off_b, mask_w, mask_b, out_w,
                                   BtI, BtOM, BtO, bOM);
  stage2_k<<<512, 512, 0, stream>>>(x, dw_w, dw_b, ln_g, ln_b, BtI, inp_b,
                                    BtOM, bOM, xpu, om);
  samp_o<<<1024, 256, 0, stream>>>(xpu, om, BtO, out_b, out);
}